// Round 4
// baseline (4686.269 us; speedup 1.0000x reference)
//
#include <hip/hip_runtime.h>
#include <stdint.h>
#include <string.h>

// UniLSTM: B=64, T=512, E=1024, H=1024.
// Phase 0: f32->f16 converts + bias sum.
// Phase 1: xprojT[T][64][4096] = (x @ W_ih^T + bsum), f16, time-major.
// Phase 2: persistent recurrence, 256 WGs x 256 thr = 4 groups x 64 unit-slices.
//   R4 design: per-STEP fresh h slots (cached, L2-shared gathers) + per-wave
//   flags after per-wave vmcnt drain (no WG barriers on producer side) +
//   quad-gate MFMA mapping (i,f,g,o of one unit in one DPP quad -> no gates
//   LDS, no barrier B). One __syncthreads per step (double-buffered h_lds).

typedef _Float16 half8 __attribute__((ext_vector_type(8)));
typedef _Float16 half4_ __attribute__((ext_vector_type(4)));
typedef float f32x4 __attribute__((ext_vector_type(4)));
typedef unsigned int u32x4 __attribute__((ext_vector_type(4)));

#define T_SEQ 512

// ---------------- converts ----------------
__global__ void k_f32_to_f16(const float* __restrict__ s, _Float16* __restrict__ d, int n4) {
  int i = blockIdx.x * blockDim.x + threadIdx.x;
  if (i >= n4) return;
  f32x4 v = ((const f32x4*)s)[i];
  half4_ h;
  h.x = (_Float16)v.x; h.y = (_Float16)v.y; h.z = (_Float16)v.z; h.w = (_Float16)v.w;
  ((half4_*)d)[i] = h;
}

__global__ void k_bias_sum(const float* __restrict__ a, const float* __restrict__ b,
                           float* __restrict__ o) {
  int i = blockIdx.x * blockDim.x + threadIdx.x;
  if (i < 4096) o[i] = a[i] + b[i];
}

// ---------------- phase 1: input projection GEMM (unchanged from R3) ----------------
__global__ __launch_bounds__(256, 2) void k_gemm_xproj(
    const _Float16* __restrict__ X, const _Float16* __restrict__ W,
    const float* __restrict__ bsum, _Float16* __restrict__ C) {
  __shared__ _Float16 As[128 * 64];
  __shared__ _Float16 Bs[128 * 64];
  const int bid = blockIdx.x;
  const int ntile = bid & 31, mtile = bid >> 5;
  const int tid = threadIdx.x;
  const int wave = tid >> 6, lane = tid & 63;
  const int wr = wave >> 1, wc = wave & 1;
  const int R0 = lane >> 3, cg = lane & 7;

  f32x4 acc[4][4];
#pragma unroll
  for (int m = 0; m < 4; m++)
#pragma unroll
    for (int n = 0; n < 4; n++) acc[m][n] = (f32x4){0.f, 0.f, 0.f, 0.f};

  for (int k0 = 0; k0 < 1024; k0 += 64) {
#pragma unroll
    for (int i = 0; i < 4; i++) {
      const int rr = (wave * 4 + i) * 8 + R0;
      const _Float16* ga = X + (size_t)(mtile * 128 + rr) * 1024 + k0 + ((cg ^ (rr & 7)) * 8);
      const _Float16* gb = W + (size_t)(ntile * 128 + rr) * 1024 + k0 + ((cg ^ (rr & 7)) * 8);
      __builtin_amdgcn_global_load_lds(
          (const __attribute__((address_space(1))) void*)ga,
          (__attribute__((address_space(3))) void*)((char*)As + (wave * 4 + i) * 1024), 16, 0, 0);
      __builtin_amdgcn_global_load_lds(
          (const __attribute__((address_space(1))) void*)gb,
          (__attribute__((address_space(3))) void*)((char*)Bs + (wave * 4 + i) * 1024), 16, 0, 0);
    }
    asm volatile("s_waitcnt vmcnt(0)" ::: "memory");
    __syncthreads();
#pragma unroll
    for (int kk = 0; kk < 2; kk++) {
      half8 af[4], bf[4];
#pragma unroll
      for (int m = 0; m < 4; m++) {
        int r = wr * 64 + m * 16 + (lane & 15);
        af[m] = *(const half8*)((const char*)As + r * 128 +
                                (((kk * 4 + (lane >> 4)) ^ (r & 7)) << 4));
      }
#pragma unroll
      for (int n = 0; n < 4; n++) {
        int r = wc * 64 + n * 16 + (lane & 15);
        bf[n] = *(const half8*)((const char*)Bs + r * 128 +
                                (((kk * 4 + (lane >> 4)) ^ (r & 7)) << 4));
      }
#pragma unroll
      for (int m = 0; m < 4; m++)
#pragma unroll
        for (int n = 0; n < 4; n++)
          acc[m][n] = __builtin_amdgcn_mfma_f32_16x16x32_f16(af[m], bf[n], acc[m][n], 0, 0, 0);
    }
    __syncthreads();
  }
#pragma unroll
  for (int n = 0; n < 4; n++) {
    int col = ntile * 128 + wc * 64 + n * 16 + (lane & 15);
    float bs = bsum[col];
#pragma unroll
    for (int m = 0; m < 4; m++)
#pragma unroll
      for (int q = 0; q < 4; q++) {
        int row = mtile * 128 + wr * 64 + m * 16 + (lane >> 4) * 4 + q;  // = b*512 + t
        int bb = row >> 9, tt = row & 511;
        C[((size_t)tt * 64 + bb) * 4096 + col] = (_Float16)(acc[m][n][q] + bs);
      }
  }
}

// DPP quad broadcast: all 4 lanes of each quad receive quad-lane K's value.
template <int CTRL>
__device__ __forceinline__ float qb(float v) {
  int i = __builtin_bit_cast(int, v);
  i = __builtin_amdgcn_update_dpp(0, i, CTRL, 0xF, 0xF, false);
  return __builtin_bit_cast(float, i);
}

// ---------------- phase 2: recurrence ----------------
// WG (g, s): XCD-swizzled so all 32 WGs on one XCD share (g, s-half) -> their
// 32KB h-slice gather is one LLC fetch + 31 L2 hits.
// Wave w, lane l: MFMA col n = l&15 -> W_hh row 1024*(n&3) + s*16 + w*4 + (n>>2)
//   (gate = n&3, unit = n>>2 -> the 4 gates of a unit live in one DPP quad).
__global__ __launch_bounds__(256, 1) void k_lstm_rec(
    const _Float16* __restrict__ Whh,     // [4096][1024] f16
    const _Float16* __restrict__ xprojT,  // [512][64][4096] f16 time-major
    const int* __restrict__ seqlen,       // [64]
    _Float16* __restrict__ hbuf,          // [513][64][1024] f16, slot t = h_t
    unsigned* __restrict__ flags,         // [513][4][64][4] u32, zeroed per launch
    float* __restrict__ out) {            // [64][1024] f32
  __shared__ _Float16 h_lds[2][16 * 1024];  // 2 x 32KB, XOR-swizzled 16B chunks

  const int bid = blockIdx.x;
  const int x8 = bid & 7;                       // XCD (assumes round-robin)
  const int g = x8 >> 1;                        // batch group 0..3
  const int s = (x8 & 1) * 32 + (bid >> 3);     // unit slice 0..63
  const int tid = threadIdx.x;
  const int wave = tid >> 6, lane = tid & 63;

  for (int i = tid; i < 4096; i += 256) ((uint64_t*)h_lds[0])[i] = 0ull;  // h_0 = 0

  // W_hh B-fragments (register-resident, quad-gate column mapping)
  const int n = lane & 15;
  half8 wfrag[32];
  {
    const _Float16* wp =
        Whh + (size_t)(1024 * (n & 3) + s * 16 + wave * 4 + (n >> 2)) * 1024 + (lane >> 4) * 8;
#pragma unroll
    for (int kk = 0; kk < 32; kk++) wfrag[kk] = *(const half8*)(wp + kk * 32);
  }

  int Lg = 1;
  for (int b = 0; b < 16; b++) {
    int L = seqlen[g * 16 + b];
    Lg = L > Lg ? L : Lg;
  }
  const int bm_st = (lane >> 4) * 4 + (lane & 3);   // batch row this lane stores
  const int mylen_st = seqlen[g * 16 + bm_st];
  const int unitF = s * 16 + wave * 4 + ((lane >> 2) & 3);  // full unit index
  const int colF = 1024 * (lane & 3) + unitF;               // xproj column

  const int rowbase = (lane & 15) * 2048;  // A-frag row byte base
  const int xorm = ((lane & 15) & 7) << 4; // A-frag XOR swizzle

  float cst[4] = {0.f, 0.f, 0.f, 0.f};  // fp32 cell state, batch rows (l>>4)*4+q

  __syncthreads();

  for (int t = 0; t < Lg; t++) {
    // xp loads (independent of h) issued before the poll
    float xp[4];
#pragma unroll
    for (int q = 0; q < 4; q++) {
      int bm = (lane >> 4) * 4 + q;
      xp[q] = (float)xprojT[((size_t)t * 64 + g * 16 + bm) * 4096 + colF];
    }

    if (t > 0) {
      // poll the 256 per-wave flags of step t (one dwordx4 per lane, LLC-bypass)
      const unsigned* fl = flags + (((size_t)t * 4 + g) << 8) + lane * 4;
      u32x4 fv;
      for (;;) {
        asm volatile("global_load_dwordx4 %0, %1, off sc0 sc1"
                     : "=v"(fv) : "v"(fl) : "memory");
        asm volatile("s_waitcnt vmcnt(0)" ::: "memory");
        bool ok = fv.x != 0u && fv.y != 0u && fv.z != 0u && fv.w != 0u;
        if (__all(ok)) break;
      }
      // gather h_t: fresh-slot addresses -> plain CACHED loads (L2-shared per XCD)
      const u32x4* src = (const u32x4*)(hbuf + (size_t)t * 65536 + (size_t)g * 16384);
      u32x4 hv[8];
#pragma unroll
      for (int i = 0; i < 8; i++) hv[i] = src[tid + (i << 8)];
#pragma unroll
      for (int i = 0; i < 8; i++) {
        int ch = tid + (i << 8);
        int b = ch >> 7, j = ch & 127;
        *(u32x4*)((char*)h_lds[t & 1] + b * 2048 + ((j ^ (b & 7)) << 4)) = hv[i];
      }
    }
    __syncthreads();  // h_lds[t&1] ready (also WAR-protects the other buffer)

    // gates: 32 MFMAs, 2 accumulator chains
    f32x4 a0 = (f32x4){0.f, 0.f, 0.f, 0.f};
    f32x4 a1 = (f32x4){0.f, 0.f, 0.f, 0.f};
    const char* lb = (const char*)h_lds[t & 1] + rowbase;
#pragma unroll
    for (int kk = 0; kk < 32; kk += 2) {
      half8 f0 = *(const half8*)(lb + ((((kk + 0) * 4 + (lane >> 4)) << 4) ^ xorm));
      half8 f1 = *(const half8*)(lb + ((((kk + 1) * 4 + (lane >> 4)) << 4) ^ xorm));
      a0 = __builtin_amdgcn_mfma_f32_16x16x32_f16(f0, wfrag[kk + 0], a0, 0, 0, 0);
      a1 = __builtin_amdgcn_mfma_f32_16x16x32_f16(f1, wfrag[kk + 1], a1, 0, 0, 0);
    }

    // elementwise: quad holds (i,f,g,o) of one unit; DPP broadcasts, all lanes
    // compute all 4 batch rows redundantly (no LDS, no barrier).
    float hq[4];
#pragma unroll
    for (int q = 0; q < 4; q++) {
      float val = (a0[q] + a1[q]) + xp[q];
      float iv = qb<0x00>(val);
      float fg = qb<0x55>(val);
      float gv = qb<0xAA>(val);
      float ov = qb<0xFF>(val);
      iv = 1.f / (1.f + __expf(-iv));
      fg = 1.f / (1.f + __expf(-fg));
      gv = 1.f - 2.f / (1.f + __expf(2.f * gv));
      ov = 1.f / (1.f + __expf(-ov));
      cst[q] = fg * cst[q] + iv * gv;
      hq[q] = ov * (1.f - 2.f / (1.f + __expf(2.f * cst[q])));
    }
    const int m = lane & 3;
    float hsel = m == 0 ? hq[0] : (m == 1 ? hq[1] : (m == 2 ? hq[2] : hq[3]));
    if (t + 1 == mylen_st) out[(size_t)(g * 16 + bm_st) * 1024 + unitF] = hsel;

    if (t + 1 < Lg) {
      _Float16 hf = (_Float16)hsel;
      unsigned short hb;
      __builtin_memcpy(&hb, &hf, 2);
      __hip_atomic_store((unsigned short*)hbuf + (size_t)(t + 1) * 65536 +
                             (size_t)(g * 16 + bm_st) * 1024 + unitF,
                         hb, __ATOMIC_RELAXED, __HIP_MEMORY_SCOPE_AGENT);
      asm volatile("s_waitcnt vmcnt(0)" ::: "memory");  // per-wave store-ack drain
      if (lane == 0)
        __hip_atomic_store(&flags[(((size_t)(t + 1) * 4 + g) << 8) + s * 4 + wave], 1u,
                           __ATOMIC_RELAXED, __HIP_MEMORY_SCOPE_AGENT);
    }
  }
}

// ---------------- launch ----------------
extern "C" void kernel_launch(void* const* d_in, const int* in_sizes, int n_in, void* d_out,
                              int out_size, void* d_ws, size_t ws_size, hipStream_t stream) {
  const float* emb = (const float*)d_in[0];   // [64,512,1024]
  const int* slen = (const int*)d_in[1];      // [64]
  const float* Wih = (const float*)d_in[2];   // [4096,1024]
  const float* Whh = (const float*)d_in[3];   // [4096,1024]
  const float* bih = (const float*)d_in[4];   // [4096]
  const float* bhh = (const float*)d_in[5];   // [4096]
  float* out = (float*)d_out;

  char* ws = (char*)d_ws;
  _Float16* xprojT = (_Float16*)(ws + 0);        // 268,435,456 B [512][64][4096]
  _Float16* xf = (_Float16*)(ws + 268435456);    //  67,108,864 B (dead after GEMM)
  _Float16* hbuf = (_Float16*)(ws + 268435456);  //  67,239,936 B [513][64][1024] (aliases xf;
                                                 //   safe: kernel-boundary acquire invalidates)
  _Float16* wihf = (_Float16*)(ws + 335675392);  //   8,388,608 B
  _Float16* whhf = (_Float16*)(ws + 344064000);  //   8,388,608 B
  float* bsum = (float*)(ws + 352452608);        //      16,384 B
  unsigned* flags = (unsigned*)(ws + 352468992); //   2,101,248 B [513][4][64][4]
  // total ws use: 354,570,240 B

  hipMemsetAsync(flags, 0, 2101248, stream);
  k_f32_to_f16<<<(8388608 + 255) / 256, 256, 0, stream>>>(emb, xf, 8388608);
  k_f32_to_f16<<<(1048576 + 255) / 256, 256, 0, stream>>>(Wih, wihf, 1048576);
  k_f32_to_f16<<<(1048576 + 255) / 256, 256, 0, stream>>>(Whh, whhf, 1048576);
  k_bias_sum<<<16, 256, 0, stream>>>(bih, bhh, bsum);
  k_gemm_xproj<<<8192, 256, 0, stream>>>(xf, wihf, bsum, xprojT);
  k_lstm_rec<<<256, 256, 0, stream>>>(whhf, xprojT, slen, hbuf, flags, out);
}

// Round 5
// 3594.107 us; speedup vs baseline: 1.3039x; 1.3039x over previous
//
#include <hip/hip_runtime.h>
#include <stdint.h>

// UniLSTM: B=64, T=512, E=1024, H=1024.
// Phase 0: f32->f16 converts + bias sum.
// Phase 1: xprojT[T][64][4096] = (x @ W_ih^T + bsum), f16, time-major.
// Phase 2: persistent recurrence, 256 WGs x 256 thr = 4 groups x 64 unit-slices.
//   R5 = R2 skeleton (wave=gate, coalesced stores, 4-expf elementwise, flags +
//   single gather) + R4's cached fresh-slot gather (L2 dedup, FETCH 704->219MB)
//   + transposed gates LDS [64][17] (kills the 4-way conflicts, 6e7 counter)
//   + per-wave flags after per-wave drain (drops barrier C) + 4 MFMA chains.

typedef _Float16 half8 __attribute__((ext_vector_type(8)));
typedef _Float16 half4_ __attribute__((ext_vector_type(4)));
typedef float f32x4 __attribute__((ext_vector_type(4)));
typedef unsigned int u32x4 __attribute__((ext_vector_type(4)));

#define T_SEQ 512

// ---------------- converts ----------------
__global__ void k_f32_to_f16(const float* __restrict__ s, _Float16* __restrict__ d, int n4) {
  int i = blockIdx.x * blockDim.x + threadIdx.x;
  if (i >= n4) return;
  f32x4 v = ((const f32x4*)s)[i];
  half4_ h;
  h.x = (_Float16)v.x; h.y = (_Float16)v.y; h.z = (_Float16)v.z; h.w = (_Float16)v.w;
  ((half4_*)d)[i] = h;
}

__global__ void k_bias_sum(const float* __restrict__ a, const float* __restrict__ b,
                           float* __restrict__ o) {
  int i = blockIdx.x * blockDim.x + threadIdx.x;
  if (i < 4096) o[i] = a[i] + b[i];
}

// ---------------- phase 1: input projection GEMM ----------------
// logical C[M=32768, N=4096] = X[M,1024] @ W[N,1024]^T + bsum[N], stored TIME-MAJOR:
// row = b*512+t -> written at C[(t*64 + b)*4096 + col]
__global__ __launch_bounds__(256, 2) void k_gemm_xproj(
    const _Float16* __restrict__ X, const _Float16* __restrict__ W,
    const float* __restrict__ bsum, _Float16* __restrict__ C) {
  __shared__ _Float16 As[128 * 64];
  __shared__ _Float16 Bs[128 * 64];
  const int bid = blockIdx.x;
  const int ntile = bid & 31, mtile = bid >> 5;
  const int tid = threadIdx.x;
  const int wave = tid >> 6, lane = tid & 63;
  const int wr = wave >> 1, wc = wave & 1;
  const int R0 = lane >> 3, cg = lane & 7;

  f32x4 acc[4][4];
#pragma unroll
  for (int m = 0; m < 4; m++)
#pragma unroll
    for (int n = 0; n < 4; n++) acc[m][n] = (f32x4){0.f, 0.f, 0.f, 0.f};

  for (int k0 = 0; k0 < 1024; k0 += 64) {
#pragma unroll
    for (int i = 0; i < 4; i++) {
      const int rr = (wave * 4 + i) * 8 + R0;
      const _Float16* ga = X + (size_t)(mtile * 128 + rr) * 1024 + k0 + ((cg ^ (rr & 7)) * 8);
      const _Float16* gb = W + (size_t)(ntile * 128 + rr) * 1024 + k0 + ((cg ^ (rr & 7)) * 8);
      __builtin_amdgcn_global_load_lds(
          (const __attribute__((address_space(1))) void*)ga,
          (__attribute__((address_space(3))) void*)((char*)As + (wave * 4 + i) * 1024), 16, 0, 0);
      __builtin_amdgcn_global_load_lds(
          (const __attribute__((address_space(1))) void*)gb,
          (__attribute__((address_space(3))) void*)((char*)Bs + (wave * 4 + i) * 1024), 16, 0, 0);
    }
    asm volatile("s_waitcnt vmcnt(0)" ::: "memory");
    __syncthreads();
#pragma unroll
    for (int kk = 0; kk < 2; kk++) {
      half8 af[4], bf[4];
#pragma unroll
      for (int m = 0; m < 4; m++) {
        int r = wr * 64 + m * 16 + (lane & 15);
        af[m] = *(const half8*)((const char*)As + r * 128 +
                                (((kk * 4 + (lane >> 4)) ^ (r & 7)) << 4));
      }
#pragma unroll
      for (int n = 0; n < 4; n++) {
        int r = wc * 64 + n * 16 + (lane & 15);
        bf[n] = *(const half8*)((const char*)Bs + r * 128 +
                                (((kk * 4 + (lane >> 4)) ^ (r & 7)) << 4));
      }
#pragma unroll
      for (int m = 0; m < 4; m++)
#pragma unroll
        for (int n = 0; n < 4; n++)
          acc[m][n] = __builtin_amdgcn_mfma_f32_16x16x32_f16(af[m], bf[n], acc[m][n], 0, 0, 0);
    }
    __syncthreads();
  }
#pragma unroll
  for (int n = 0; n < 4; n++) {
    int col = ntile * 128 + wc * 64 + n * 16 + (lane & 15);
    float bs = bsum[col];
#pragma unroll
    for (int m = 0; m < 4; m++)
#pragma unroll
      for (int q = 0; q < 4; q++) {
        int row = mtile * 128 + wr * 64 + m * 16 + (lane >> 4) * 4 + q;  // = b*512 + t
        int bb = row >> 9, tt = row & 511;
        C[((size_t)tt * 64 + bb) * 4096 + col] = (_Float16)(acc[m][n][q] + bs);
      }
  }
}

// ---------------- phase 2: recurrence ----------------
// WG (g, s): g = (bid&7)>>1, s = (bid&1mask...)  XCD-swizzle: all 32 WGs on one
// XCD share (g, s-half) -> group h-slice + xprojT slab are fetched ~once per XCD.
// Wave w = gate w (i,f,g,o); MFMA col n = unit s*16+n -> W_hh row 1024*w + s*16 + n.
__global__ __launch_bounds__(256, 1) void k_lstm_rec(
    const _Float16* __restrict__ Whh,     // [4096][1024] f16
    const _Float16* __restrict__ xprojT,  // [512][64][4096] f16 time-major
    const int* __restrict__ seqlen,       // [64]
    _Float16* __restrict__ hbuf,          // [512][64][1024] f16, slot t = h_t (t>=1)
    unsigned* __restrict__ flags,         // [512][4][64][4] u32, zeroed per launch
    float* __restrict__ out) {            // [64][1024] f32
  __shared__ _Float16 h_lds[16 * 1024];  // 32 KB, XOR-swizzled 16B chunks
  __shared__ float gates[64 * 17];       // transposed [col][row], pad 17 (<=2-way banks)

  const int bid = blockIdx.x;
  const int x8 = bid & 7;                    // XCD (perf-only assumption)
  const int g = x8 >> 1;                     // batch group 0..3
  const int s = (x8 & 1) * 32 + (bid >> 3);  // unit slice 0..63
  const int tid = threadIdx.x;
  const int wave = tid >> 6, lane = tid & 63;

  for (int i = tid; i < 4096; i += 256) ((uint64_t*)h_lds)[i] = 0ull;  // h_0 = 0

  // W_hh B-fragments, register-resident (R2 mapping, validated)
  half8 wfrag[32];
  {
    const _Float16* wp =
        Whh + (size_t)(1024 * wave + s * 16 + (lane & 15)) * 1024 + (lane >> 4) * 8;
#pragma unroll
    for (int kk = 0; kk < 32; kk++) wfrag[kk] = *(const half8*)(wp + kk * 32);
  }

  int Lg = 1;
  for (int b = 0; b < 16; b++) {
    int L = seqlen[g * 16 + b];
    Lg = L > Lg ? L : Lg;
  }
  const int be = tid >> 4, ue = tid & 15;  // elementwise cell (batch row, unit)
  const int mylen = seqlen[g * 16 + be];
  float c_state = 0.f;

  const int rowbase = (lane & 15) * 2048;   // A-frag row byte base
  const int xorm = ((lane & 15) & 7) << 4;  // A-frag XOR swizzle

  __syncthreads();  // h_lds init visible (serves as barrier A for t=0)

  for (int t = 0; t < Lg; t++) {
    // xp loads (independent of h), issued before the poll
    float xp[4];
#pragma unroll
    for (int q = 0; q < 4; q++) {
      int bm = (lane >> 4) * 4 + q;
      xp[q] = (float)xprojT[((size_t)t * 64 + g * 16 + bm) * 4096 + 1024 * wave + s * 16 +
                            (lane & 15)];
    }

    if (t > 0) {
      // poll 256 per-wave flags of (t, g): one dwordx4 per lane, LLC-bypass
      const unsigned* fl = flags + (((size_t)t * 4 + g) << 8) + lane * 4;
      u32x4 fv;
      for (;;) {
        asm volatile("global_load_dwordx4 %0, %1, off sc0 sc1"
                     : "=v"(fv) : "v"(fl) : "memory");
        asm volatile("s_waitcnt vmcnt(0)" ::: "memory");
        bool ok = fv.x != 0u && fv.y != 0u && fv.z != 0u && fv.w != 0u;
        if (__all(ok)) break;
      }
      // gather h_t: fresh-slot addresses -> plain CACHED loads (L2-dedup per XCD)
      const u32x4* src = (const u32x4*)(hbuf + (size_t)t * 65536 + (size_t)g * 16384);
      u32x4 hv[8];
#pragma unroll
      for (int i = 0; i < 8; i++) hv[i] = src[tid + (i << 8)];
#pragma unroll
      for (int i = 0; i < 8; i++) {
        int ch = tid + (i << 8);
        int b = ch >> 7, j = ch & 127;
        *(u32x4*)((char*)h_lds + b * 2048 + ((j ^ (b & 7)) << 4)) = hv[i];
      }
    }
    __syncthreads();  // (A) h_lds ready; also WAR-protects gates

    // gates: M=16 x N=16, K=1024 -> 32 MFMAs in 4 accumulator chains
    f32x4 a0 = (f32x4){0.f, 0.f, 0.f, 0.f};
    f32x4 a1 = (f32x4){0.f, 0.f, 0.f, 0.f};
    f32x4 a2 = (f32x4){0.f, 0.f, 0.f, 0.f};
    f32x4 a3 = (f32x4){0.f, 0.f, 0.f, 0.f};
    const char* lb = (const char*)h_lds + rowbase;
#pragma unroll
    for (int kk = 0; kk < 32; kk += 4) {
      half8 f0 = *(const half8*)(lb + ((((kk + 0) * 4 + (lane >> 4)) << 4) ^ xorm));
      half8 f1 = *(const half8*)(lb + ((((kk + 1) * 4 + (lane >> 4)) << 4) ^ xorm));
      half8 f2 = *(const half8*)(lb + ((((kk + 2) * 4 + (lane >> 4)) << 4) ^ xorm));
      half8 f3 = *(const half8*)(lb + ((((kk + 3) * 4 + (lane >> 4)) << 4) ^ xorm));
      a0 = __builtin_amdgcn_mfma_f32_16x16x32_f16(f0, wfrag[kk + 0], a0, 0, 0, 0);
      a1 = __builtin_amdgcn_mfma_f32_16x16x32_f16(f1, wfrag[kk + 1], a1, 0, 0, 0);
      a2 = __builtin_amdgcn_mfma_f32_16x16x32_f16(f2, wfrag[kk + 2], a2, 0, 0, 0);
      a3 = __builtin_amdgcn_mfma_f32_16x16x32_f16(f3, wfrag[kk + 3], a3, 0, 0, 0);
    }
    // transposed gates store: col = wave*16 + u, rows bm0..bm0+3 -> one f32x4
    {
      f32x4 gv4;
#pragma unroll
      for (int q = 0; q < 4; q++) gv4[q] = (a0[q] + a1[q]) + (a2[q] + a3[q]) + xp[q];
      *(f32x4*)&gates[(wave * 16 + (lane & 15)) * 17 + (lane >> 4) * 4] = gv4;
    }
    __syncthreads();  // (B) gates ready

    // elementwise: thread owns (be, ue); reads 4 gate cols transposed
    float iv = gates[(0 + ue) * 17 + be];
    float fv = gates[(16 + ue) * 17 + be];
    float gv = gates[(32 + ue) * 17 + be];
    float ov = gates[(48 + ue) * 17 + be];
    iv = 1.f / (1.f + __expf(-iv));
    fv = 1.f / (1.f + __expf(-fv));
    gv = 1.f - 2.f / (1.f + __expf(2.f * gv));
    ov = 1.f / (1.f + __expf(-ov));
    c_state = fv * c_state + iv * gv;
    float tc = 1.f - 2.f / (1.f + __expf(2.f * c_state));
    float hv = ov * tc;
    if (t + 1 == mylen) out[(size_t)(g * 16 + be) * 1024 + s * 16 + ue] = hv;

    if (t + 1 < Lg) {
      _Float16 hf = (_Float16)hv;
      unsigned short hb;
      __builtin_memcpy(&hb, &hf, 2);
      // coalesced (32B / 16 lanes) agent-scope store -> LLC-visible
      __hip_atomic_store((unsigned short*)hbuf + (size_t)(t + 1) * 65536 +
                             (size_t)(g * 16 + be) * 1024 + s * 16 + ue,
                         hb, __ATOMIC_RELAXED, __HIP_MEMORY_SCOPE_AGENT);
      asm volatile("s_waitcnt vmcnt(0)" ::: "memory");  // per-wave store-ack drain
      if (lane == 0)
        __hip_atomic_store(&flags[(((size_t)(t + 1) * 4 + g) << 8) + s * 4 + wave], 1u,
                           __ATOMIC_RELAXED, __HIP_MEMORY_SCOPE_AGENT);
    }
  }
}

// ---------------- launch ----------------
extern "C" void kernel_launch(void* const* d_in, const int* in_sizes, int n_in, void* d_out,
                              int out_size, void* d_ws, size_t ws_size, hipStream_t stream) {
  const float* emb = (const float*)d_in[0];   // [64,512,1024]
  const int* slen = (const int*)d_in[1];      // [64]
  const float* Wih = (const float*)d_in[2];   // [4096,1024]
  const float* Whh = (const float*)d_in[3];   // [4096,1024]
  const float* bih = (const float*)d_in[4];   // [4096]
  const float* bhh = (const float*)d_in[5];   // [4096]
  float* out = (float*)d_out;

  char* ws = (char*)d_ws;
  _Float16* xprojT = (_Float16*)(ws + 0);        // 268,435,456 B [512][64][4096]
  _Float16* xf = (_Float16*)(ws + 268435456);    //  67,108,864 B (dead after GEMM)
  _Float16* hbuf = (_Float16*)(ws + 268435456);  //  67,108,864 B [512][64][1024] (aliases xf)
  _Float16* wihf = (_Float16*)(ws + 335544320);  //   8,388,608 B
  _Float16* whhf = (_Float16*)(ws + 343932928);  //   8,388,608 B
  float* bsum = (float*)(ws + 352321536);        //      16,384 B
  unsigned* flags = (unsigned*)(ws + 352337920); //   2,097,152 B [512][4][64][4]
  // total ws use: 354,435,072 B

  hipMemsetAsync(flags, 0, 2097152, stream);
  k_f32_to_f16<<<(8388608 + 255) / 256, 256, 0, stream>>>(emb, xf, 8388608);
  k_f32_to_f16<<<(1048576 + 255) / 256, 256, 0, stream>>>(Wih, wihf, 1048576);
  k_f32_to_f16<<<(1048576 + 255) / 256, 256, 0, stream>>>(Whh, whhf, 1048576);
  k_bias_sum<<<16, 256, 0, stream>>>(bih, bhh, bsum);
  k_gemm_xproj<<<8192, 256, 0, stream>>>(xf, wihf, bsum, xprojT);
  k_lstm_rec<<<256, 256, 0, stream>>>(whhf, xprojT, slen, hbuf, flags, out);
}

// Round 6
// 1948.452 us; speedup vs baseline: 2.4051x; 1.8446x over previous
//
#include <hip/hip_runtime.h>
#include <stdint.h>

// UniLSTM: B=64, T=512, E=1024, H=1024.
// Phase 0: f32->f16 converts + bias sum.
// Phase 1: xprojT[T][64][4096] = (x @ W_ih^T + bsum), f16, time-major.
// Phase 2: persistent recurrence, 256 WGs x 256 thr = 4 groups x 64 unit-slices.
//   R6: TAGGED ping-pong h exchange. h stored as ((t+1)<<16|h_f16) u32 in an
//   LLC-resident ping-pong buffer (R2's residency => store hits). The gather
//   IS the poll: bypass-read 16B chunks, validate 4 tags each, selectively
//   re-read only pending chunks (fixes R3's bulk-repoll death). Producer has
//   NO drain, NO flag, NO barrier C — readiness travels with the data.

typedef _Float16 half8 __attribute__((ext_vector_type(8)));
typedef _Float16 half4_ __attribute__((ext_vector_type(4)));
typedef float f32x4 __attribute__((ext_vector_type(4)));
typedef unsigned int u32x4 __attribute__((ext_vector_type(4)));

#define T_SEQ 512

// ---------------- converts ----------------
__global__ void k_f32_to_f16(const float* __restrict__ s, _Float16* __restrict__ d, int n4) {
  int i = blockIdx.x * blockDim.x + threadIdx.x;
  if (i >= n4) return;
  f32x4 v = ((const f32x4*)s)[i];
  half4_ h;
  h.x = (_Float16)v.x; h.y = (_Float16)v.y; h.z = (_Float16)v.z; h.w = (_Float16)v.w;
  ((half4_*)d)[i] = h;
}

__global__ void k_bias_sum(const float* __restrict__ a, const float* __restrict__ b,
                           float* __restrict__ o) {
  int i = blockIdx.x * blockDim.x + threadIdx.x;
  if (i < 4096) o[i] = a[i] + b[i];
}

// ---------------- phase 1: input projection GEMM ----------------
// logical C[M=32768, N=4096] = X[M,1024] @ W[N,1024]^T + bsum[N], stored TIME-MAJOR:
// row = b*512+t -> written at C[(t*64 + b)*4096 + col]
__global__ __launch_bounds__(256, 2) void k_gemm_xproj(
    const _Float16* __restrict__ X, const _Float16* __restrict__ W,
    const float* __restrict__ bsum, _Float16* __restrict__ C) {
  __shared__ _Float16 As[128 * 64];
  __shared__ _Float16 Bs[128 * 64];
  const int bid = blockIdx.x;
  const int ntile = bid & 31, mtile = bid >> 5;
  const int tid = threadIdx.x;
  const int wave = tid >> 6, lane = tid & 63;
  const int wr = wave >> 1, wc = wave & 1;
  const int R0 = lane >> 3, cg = lane & 7;

  f32x4 acc[4][4];
#pragma unroll
  for (int m = 0; m < 4; m++)
#pragma unroll
    for (int n = 0; n < 4; n++) acc[m][n] = (f32x4){0.f, 0.f, 0.f, 0.f};

  for (int k0 = 0; k0 < 1024; k0 += 64) {
#pragma unroll
    for (int i = 0; i < 4; i++) {
      const int rr = (wave * 4 + i) * 8 + R0;
      const _Float16* ga = X + (size_t)(mtile * 128 + rr) * 1024 + k0 + ((cg ^ (rr & 7)) * 8);
      const _Float16* gb = W + (size_t)(ntile * 128 + rr) * 1024 + k0 + ((cg ^ (rr & 7)) * 8);
      __builtin_amdgcn_global_load_lds(
          (const __attribute__((address_space(1))) void*)ga,
          (__attribute__((address_space(3))) void*)((char*)As + (wave * 4 + i) * 1024), 16, 0, 0);
      __builtin_amdgcn_global_load_lds(
          (const __attribute__((address_space(1))) void*)gb,
          (__attribute__((address_space(3))) void*)((char*)Bs + (wave * 4 + i) * 1024), 16, 0, 0);
    }
    asm volatile("s_waitcnt vmcnt(0)" ::: "memory");
    __syncthreads();
#pragma unroll
    for (int kk = 0; kk < 2; kk++) {
      half8 af[4], bf[4];
#pragma unroll
      for (int m = 0; m < 4; m++) {
        int r = wr * 64 + m * 16 + (lane & 15);
        af[m] = *(const half8*)((const char*)As + r * 128 +
                                (((kk * 4 + (lane >> 4)) ^ (r & 7)) << 4));
      }
#pragma unroll
      for (int n = 0; n < 4; n++) {
        int r = wc * 64 + n * 16 + (lane & 15);
        bf[n] = *(const half8*)((const char*)Bs + r * 128 +
                                (((kk * 4 + (lane >> 4)) ^ (r & 7)) << 4));
      }
#pragma unroll
      for (int m = 0; m < 4; m++)
#pragma unroll
        for (int n = 0; n < 4; n++)
          acc[m][n] = __builtin_amdgcn_mfma_f32_16x16x32_f16(af[m], bf[n], acc[m][n], 0, 0, 0);
    }
    __syncthreads();
  }
#pragma unroll
  for (int n = 0; n < 4; n++) {
    int col = ntile * 128 + wc * 64 + n * 16 + (lane & 15);
    float bs = bsum[col];
#pragma unroll
    for (int m = 0; m < 4; m++)
#pragma unroll
      for (int q = 0; q < 4; q++) {
        int row = mtile * 128 + wr * 64 + m * 16 + (lane >> 4) * 4 + q;  // = b*512 + t
        int bb = row >> 9, tt = row & 511;
        C[((size_t)tt * 64 + bb) * 4096 + col] = (_Float16)(acc[m][n][q] + bs);
      }
  }
}

// ---------------- phase 2: recurrence ----------------
// WG (g, s): XCD-swizzled (perf-only): g=(bid&7)>>1, s=(bid&1)*32+(bid>>3).
// Wave w = gate w; MFMA col n = unit s*16+n -> W_hh row 1024*w + s*16 + n.
// Exchange: hbuf u32[2][64][1024] ping-pong of tagged words ((t+1)<<16|h16).
// Consumer polls buf[t&1] until every chunk's 4 tags == t; pending-only rereads.
__global__ __launch_bounds__(256, 1) void k_lstm_rec(
    const _Float16* __restrict__ Whh,     // [4096][1024] f16
    const _Float16* __restrict__ xprojT,  // [512][64][4096] f16 time-major
    const int* __restrict__ seqlen,       // [64]
    unsigned* __restrict__ hbuf,          // [2][64][1024] tagged u32, zeroed per launch
    float* __restrict__ out) {            // [64][1024] f32
  __shared__ _Float16 h_lds[16 * 1024];  // 32 KB packed f16, XOR-swizzled 16B chunks
  __shared__ float gates[64 * 17];       // transposed [col][row], pad 17

  const int bid = blockIdx.x;
  const int x8 = bid & 7;                    // XCD (perf heuristic only)
  const int g = x8 >> 1;                     // batch group 0..3
  const int s = (x8 & 1) * 32 + (bid >> 3);  // unit slice 0..63
  const int tid = threadIdx.x;
  const int wave = tid >> 6, lane = tid & 63;

  for (int i = tid; i < 4096; i += 256) ((uint64_t*)h_lds)[i] = 0ull;  // h_0 = 0

  // W_hh B-fragments, register-resident (mapping validated R2/R5)
  half8 wfrag[32];
  {
    const _Float16* wp =
        Whh + (size_t)(1024 * wave + s * 16 + (lane & 15)) * 1024 + (lane >> 4) * 8;
#pragma unroll
    for (int kk = 0; kk < 32; kk++) wfrag[kk] = *(const half8*)(wp + kk * 32);
  }

  int Lg = 1;
  for (int b = 0; b < 16; b++) {
    int L = seqlen[g * 16 + b];
    Lg = L > Lg ? L : Lg;
  }
  const int be = tid >> 4, ue = tid & 15;  // elementwise cell (batch row, unit)
  const int mylen = seqlen[g * 16 + be];
  float c_state = 0.f;

  const int rowbase = (lane & 15) * 2048;   // A-frag row byte base
  const int xorm = ((lane & 15) & 7) << 4;  // A-frag XOR swizzle

  __syncthreads();  // h_lds zeros visible for t=0

  for (int t = 0; t < Lg; t++) {
    // xp loads (independent of h), issued before the poll-gather
    float xp[4];
#pragma unroll
    for (int q = 0; q < 4; q++) {
      int bm = (lane >> 4) * 4 + q;
      xp[q] = (float)xprojT[((size_t)t * 64 + g * 16 + bm) * 4096 + 1024 * wave + s * 16 +
                            (lane & 15)];
    }

    if (t > 0) {
      // poll-gather: 16 sweeps-chunks/thread over [16][1024] tagged u32 (64KB/WG).
      // chunk ch = tid + idx*256 -> row = idx (whole WG loads one row per idx).
      const unsigned* src = hbuf + ((size_t)(t & 1)) * 65536 + (size_t)g * 16384;
      const unsigned Etag = (unsigned)t << 16;
#pragma unroll
      for (int hf = 0; hf < 2; hf++) {  // two halves of 8 chunks (VGPR cap)
        u32x4 hv[8];
        unsigned done = 0;
        while (done != 0xFFu) {
#pragma unroll
          for (int i = 0; i < 8; i++) {
            if (!(done & (1u << i))) {
              asm volatile("global_load_dwordx4 %0, %1, off sc0 sc1"
                           : "=v"(hv[i])
                           : "v"(src + (size_t)(tid + ((hf * 8 + i) << 8)) * 4)
                           : "memory");
            }
          }
          asm volatile("s_waitcnt vmcnt(0)" ::: "memory");
#pragma unroll
          for (int i = 0; i < 8; i++) {
            if (!(done & (1u << i))) {
              unsigned m = ((hv[i].x ^ Etag) | (hv[i].y ^ Etag) | (hv[i].z ^ Etag) |
                            (hv[i].w ^ Etag)) & 0xFFFF0000u;
              if (__all(m == 0u)) done |= 1u << i;
            }
          }
        }
        // strip tags, pack 4 u32 -> 8B f16, write swizzled LDS
#pragma unroll
        for (int i = 0; i < 8; i++) {
          int ch = tid + ((hf * 8 + i) << 8);
          int br = ch >> 8, cidx = ch & 255;
          unsigned lo = (hv[i].x & 0xFFFFu) | (hv[i].y << 16);
          unsigned hi = (hv[i].z & 0xFFFFu) | (hv[i].w << 16);
          *(uint64_t*)((char*)h_lds + br * 2048 + (((cidx >> 1) ^ (br & 7)) << 4) +
                       (cidx & 1) * 8) = (uint64_t)lo | ((uint64_t)hi << 32);
        }
      }
    }
    __syncthreads();  // (A) h_lds ready; also WAR-protects gates

    // gates: M=16 x N=16, K=1024 -> 32 MFMAs in 4 accumulator chains
    f32x4 a0 = (f32x4){0.f, 0.f, 0.f, 0.f};
    f32x4 a1 = (f32x4){0.f, 0.f, 0.f, 0.f};
    f32x4 a2 = (f32x4){0.f, 0.f, 0.f, 0.f};
    f32x4 a3 = (f32x4){0.f, 0.f, 0.f, 0.f};
    const char* lb = (const char*)h_lds + rowbase;
#pragma unroll
    for (int kk = 0; kk < 32; kk += 4) {
      half8 f0 = *(const half8*)(lb + ((((kk + 0) * 4 + (lane >> 4)) << 4) ^ xorm));
      half8 f1 = *(const half8*)(lb + ((((kk + 1) * 4 + (lane >> 4)) << 4) ^ xorm));
      half8 f2 = *(const half8*)(lb + ((((kk + 2) * 4 + (lane >> 4)) << 4) ^ xorm));
      half8 f3 = *(const half8*)(lb + ((((kk + 3) * 4 + (lane >> 4)) << 4) ^ xorm));
      a0 = __builtin_amdgcn_mfma_f32_16x16x32_f16(f0, wfrag[kk + 0], a0, 0, 0, 0);
      a1 = __builtin_amdgcn_mfma_f32_16x16x32_f16(f1, wfrag[kk + 1], a1, 0, 0, 0);
      a2 = __builtin_amdgcn_mfma_f32_16x16x32_f16(f2, wfrag[kk + 2], a2, 0, 0, 0);
      a3 = __builtin_amdgcn_mfma_f32_16x16x32_f16(f3, wfrag[kk + 3], a3, 0, 0, 0);
    }
    {
      f32x4 gv4;
#pragma unroll
      for (int q = 0; q < 4; q++) gv4[q] = (a0[q] + a1[q]) + (a2[q] + a3[q]) + xp[q];
      *(f32x4*)&gates[(wave * 16 + (lane & 15)) * 17 + (lane >> 4) * 4] = gv4;
    }
    __syncthreads();  // (B) gates ready

    // elementwise: thread owns (be, ue)
    float iv = gates[(0 + ue) * 17 + be];
    float fv = gates[(16 + ue) * 17 + be];
    float gv = gates[(32 + ue) * 17 + be];
    float ov = gates[(48 + ue) * 17 + be];
    iv = 1.f / (1.f + __expf(-iv));
    fv = 1.f / (1.f + __expf(-fv));
    gv = 1.f - 2.f / (1.f + __expf(2.f * gv));
    ov = 1.f / (1.f + __expf(-ov));
    c_state = fv * c_state + iv * gv;
    float tc = 1.f - 2.f / (1.f + __expf(2.f * c_state));
    float hv = ov * tc;
    if (t + 1 == mylen) out[(size_t)(g * 16 + be) * 1024 + s * 16 + ue] = hv;

    if (t + 1 < Lg) {
      _Float16 hfv = (_Float16)hv;
      unsigned short hb;
      __builtin_memcpy(&hb, &hfv, 2);
      unsigned tw = ((unsigned)(t + 1) << 16) | (unsigned)hb;
      // tagged store: 16 lanes x 4B = 64B full-sector, LLC-resident ping-pong
      __hip_atomic_store(hbuf + ((size_t)((t + 1) & 1)) * 65536 +
                             (size_t)(g * 16 + be) * 1024 + s * 16 + ue,
                         tw, __ATOMIC_RELAXED, __HIP_MEMORY_SCOPE_AGENT);
      // no drain, no flag, no barrier — readiness travels with the data
    }
  }
}

// ---------------- launch ----------------
extern "C" void kernel_launch(void* const* d_in, const int* in_sizes, int n_in, void* d_out,
                              int out_size, void* d_ws, size_t ws_size, hipStream_t stream) {
  const float* emb = (const float*)d_in[0];   // [64,512,1024]
  const int* slen = (const int*)d_in[1];      // [64]
  const float* Wih = (const float*)d_in[2];   // [4096,1024]
  const float* Whh = (const float*)d_in[3];   // [4096,1024]
  const float* bih = (const float*)d_in[4];   // [4096]
  const float* bhh = (const float*)d_in[5];   // [4096]
  float* out = (float*)d_out;

  char* ws = (char*)d_ws;
  _Float16* xprojT = (_Float16*)(ws + 0);        // 268,435,456 B [512][64][4096]
  _Float16* xf = (_Float16*)(ws + 268435456);    //  67,108,864 B (dead after GEMM)
  unsigned* hbuf = (unsigned*)(ws + 268435456);  //     524,288 B [2][64][1024] u32 (aliases xf)
  _Float16* wihf = (_Float16*)(ws + 335544320);  //   8,388,608 B
  _Float16* whhf = (_Float16*)(ws + 343932928);  //   8,388,608 B
  float* bsum = (float*)(ws + 352321536);        //      16,384 B
  // total ws use: 352,337,920 B

  k_f32_to_f16<<<(8388608 + 255) / 256, 256, 0, stream>>>(emb, xf, 8388608);
  k_f32_to_f16<<<(1048576 + 255) / 256, 256, 0, stream>>>(Wih, wihf, 1048576);
  k_f32_to_f16<<<(1048576 + 255) / 256, 256, 0, stream>>>(Whh, whhf, 1048576);
  k_bias_sum<<<16, 256, 0, stream>>>(bih, bhh, bsum);
  k_gemm_xproj<<<8192, 256, 0, stream>>>(xf, wihf, bsum, xprojT);
  // zero ALL tags AFTER the GEMM consumed xf (hbuf aliases xf); tag 0 never polled
  hipMemsetAsync(hbuf, 0, 524288, stream);
  k_lstm_rec<<<256, 256, 0, stream>>>(whhf, xprojT, slen, hbuf, out);
}